// Round 6
// baseline (471.840 us; speedup 1.0000x reference)
//
#include <hip/hip_runtime.h>

namespace {

constexpr int kN = 50000, kE = 200000, kG = 500;
constexpr float kEps = 1e-5f;

typedef short v8s __attribute__((ext_vector_type(8)));
typedef float v4f __attribute__((ext_vector_type(4)));

__device__ __forceinline__ unsigned short bf16rn(float x) {
    unsigned u = __float_as_uint(x);
    return (unsigned short)((u + 0x7FFFu + ((u >> 16) & 1u)) >> 16);
}
__device__ __forceinline__ float bf16lo(unsigned p) { return __uint_as_float(p << 16); }
__device__ __forceinline__ float bf16hi(unsigned p) { return __uint_as_float(p & 0xFFFF0000u); }
__device__ __forceinline__ unsigned pk2(float a, float b) {
    return (unsigned)bf16rn(a) | ((unsigned)bf16rn(b) << 16);
}

// ---- zero deg + stats (ws is re-poisoned to 0xAA before every call). ----
__global__ __launch_bounds__(256) void zero_init(int* __restrict__ deg,
                                                 float* __restrict__ stats) {
    int i = blockIdx.x * 256 + threadIdx.x;
    if (i < kN) deg[i] = 0;
    if (i < 192) stats[i] = 0.f;
}

// ---- h = leaky(x @ lin_W + lin_b), fp32 [n][c], MFMA (A=nodes). ----
__global__ __launch_bounds__(1024) void init_h(
    const float* __restrict__ x, const float* __restrict__ W,
    const float* __restrict__ b, float* __restrict__ hbuf)
{
    __shared__ unsigned short sx[256 * 96];   // [node][feat pad96]
    __shared__ unsigned short sW[32 * 96];    // [c][feat pad96]
    int t = threadIdx.x;
    for (int i = t; i < 256 * 96; i += 1024) sx[i] = 0;
    for (int i = t; i < 32 * 96; i += 1024) sW[i] = 0;
    __syncthreads();
    int tb = blockIdx.x * 256;
    int cnt = min(256, kN - tb);
    for (int i = t; i < cnt * 75; i += 1024) {
        int n = i / 75, f = i - n * 75;
        sx[n * 96 + f] = bf16rn(x[(size_t)tb * 75 + i]);
    }
    for (int i = t; i < 75 * 32; i += 1024) {
        int f = i >> 5, c = i & 31;
        sW[c * 96 + f] = bf16rn(W[i]);
    }
    __syncthreads();
    int l15 = t & 15, quad = (t >> 4) & 3, w = t >> 6;
    #pragma unroll
    for (int tile = 0; tile < 2; ++tile) {
        v4f acc = {0.f, 0.f, 0.f, 0.f};
        #pragma unroll
        for (int kc = 0; kc < 3; ++kc) {
            v8s a  = *(const v8s*)&sx[(w * 16 + l15) * 96 + kc * 32 + quad * 8];
            v8s bb = *(const v8s*)&sW[(tile * 16 + l15) * 96 + kc * 32 + quad * 8];
            acc = __builtin_amdgcn_mfma_f32_16x16x32_bf16(a, bb, acc, 0, 0, 0);
        }
        int c = tile * 16 + l15;
        float bc = b[c];
        #pragma unroll
        for (int r = 0; r < 4; ++r) {
            int n = tb + w * 16 + quad * 4 + r;
            if (n < kN) {
                float v = acc[r] + bc;
                hbuf[(size_t)n * 32 + c] = v > 0.f ? v : 0.01f * v;   // coalesced
            }
        }
    }
}

// ---- hid = relu(ea@W1+b1) for 3 layers (bf16-packed) + deg histogram. ----
__global__ __launch_bounds__(256) void hid_pre(
    const float* __restrict__ ea, const float* __restrict__ W1,
    const float* __restrict__ b1, const int* __restrict__ ei,
    unsigned* __restrict__ hidpk, int* __restrict__ deg)
{
    __shared__ float sE[256 * 13];
    __shared__ float sW[195];
    int t = threadIdx.x;
    for (int i = t; i < 195; i += 256) sW[i] = (i < 180) ? W1[i] : b1[i - 180];
    int base = blockIdx.x * 256;
    int cnt = min(256, kE - base);
    for (int i = t; i < cnt * 12; i += 256) {
        int el = i / 12, f = i - el * 12;
        sE[el * 13 + f] = ea[(size_t)base * 12 + i];
    }
    __syncthreads();
    if (t >= cnt) return;
    int e = base + t;
    atomicAdd(&deg[ei[kE + e]], 1);
    float ef[12];
    #pragma unroll
    for (int j = 0; j < 12; ++j) ef[j] = sE[t * 13 + j];
    #pragma unroll
    for (int l = 0; l < 3; ++l) {
        float h[5];
        #pragma unroll
        for (int k = 0; k < 5; ++k) h[k] = sW[180 + l * 5 + k];
        #pragma unroll
        for (int f = 0; f < 12; ++f)
            #pragma unroll
            for (int k = 0; k < 5; ++k)
                h[k] = fmaf(ef[f], sW[l * 60 + f * 5 + k], h[k]);
        #pragma unroll
        for (int k = 0; k < 5; ++k) h[k] = h[k] > 0.f ? h[k] : 0.f;
        size_t o = ((size_t)l * kE + e) * 3;
        hidpk[o + 0] = pk2(h[0], h[1]);
        hidpk[o + 1] = pk2(h[2], h[3]);
        hidpk[o + 2] = pk2(h[4], 0.f);
    }
}

// ---- exclusive scan of deg -> rowptr & cursor (single block). ----
__global__ __launch_bounds__(1024) void csr_scan(
    const int* __restrict__ deg, int* __restrict__ rowptr,
    int* __restrict__ cursor)
{
    __shared__ int sc[1024];
    const int C = 49;                 // 1024*49 = 50176 >= kN
    int t = threadIdx.x;
    int base = t * C;
    int s = 0;
    for (int i = 0; i < C; ++i) {
        int idx = base + i;
        if (idx < kN) s += deg[idx];
    }
    sc[t] = s;
    __syncthreads();
    for (int off = 1; off < 1024; off <<= 1) {
        int v = (t >= off) ? sc[t - off] : 0;
        __syncthreads();
        sc[t] += v;
        __syncthreads();
    }
    int p = sc[t] - s;                // exclusive prefix
    for (int i = 0; i < C; ++i) {
        int idx = base + i;
        if (idx < kN) {
            rowptr[idx] = p;
            cursor[idx] = p;
            p += deg[idx];
        }
    }
    if (t == 1023) rowptr[kN] = p;
}

// ---- scatter edges into CSR order (by dst). ----
__global__ __launch_bounds__(256) void csr_fill(
    const int* __restrict__ ei, int* __restrict__ cursor,
    int* __restrict__ csr_src, int* __restrict__ csr_eid)
{
    int e = blockIdx.x * 256 + threadIdx.x;
    if (e >= kE) return;
    int dst = ei[kE + e];
    int pos = atomicAdd(&cursor[dst], 1);
    csr_src[pos] = ei[e];
    csr_eid[pos] = e;
}

// ---- y_root: [256n,32] @ [32,224] MFMA (A=nodes). Y fp32 [n][k][d], k-major
// cols -> coalesced stores. k<6 -> Y, k==6 -> obuf=root+conv_b. BN fused. ----
__global__ __launch_bounds__(1024) void y_root(
    const float* __restrict__ hbuf, float* __restrict__ obuf,
    const float* __restrict__ W2, const float* __restrict__ b2,
    const float* __restrict__ rW, const float* __restrict__ convb,
    const float* __restrict__ stats,
    const float* __restrict__ gPrev, const float* __restrict__ bPrev,
    int first, float* __restrict__ Yf)
{
    __shared__ unsigned short sh[256 * 32];   // [node][c]
    __shared__ unsigned short sB[224 * 32];   // [co=k*32+d][c]
    int t = threadIdx.x;
    int tb = blockIdx.x * 256;
    int cnt = min(256, kN - tb);
    for (int i = t; i < 224 * 32; i += 1024) {
        int co = i >> 5, c = i & 31, k = co >> 5, d = co & 31;
        float v = (k < 5) ? W2[k * 1024 + c * 32 + d]
                : (k == 5) ? b2[c * 32 + d] : rW[c * 32 + d];
        sB[co * 32 + c] = bf16rn(v);
    }
    if (first) {
        #pragma unroll
        for (int j = 0; j < 8; ++j) {
            int idx = t + j * 1024;
            int nl = idx >> 5, c = idx & 31;
            float v = (nl < cnt) ? hbuf[(size_t)(tb + nl) * 32 + c] : 0.f;
            sh[idx] = bf16rn(v);
        }
    } else {
        int c = t & 31;
        float mu = stats[c] * (1.f / kN);
        float var = stats[32 + c] * (1.f / kN) - mu * mu;
        float ivg = rsqrtf(var + kEps) * gPrev[c];
        float bb = bPrev[c];
        #pragma unroll
        for (int j = 0; j < 8; ++j) {
            int idx = t + j * 1024;
            int nl = idx >> 5;
            float v = 0.f;
            if (nl < cnt) {
                float o = obuf[(size_t)(tb + nl) * 32 + c];
                v = (o - mu) * ivg + bb;
                v = v > 0.f ? v : 0.01f * v;
            }
            sh[idx] = bf16rn(v);
        }
    }
    __syncthreads();
    int l15 = t & 15, quad = (t >> 4) & 3, w = t >> 6;
    v8s a = *(const v8s*)&sh[(w * 16 + l15) * 32 + quad * 8];
    #pragma unroll
    for (int i = 0; i < 14; ++i) {
        v8s bb = *(const v8s*)&sB[(i * 16 + l15) * 32 + quad * 8];
        v4f acc = {0.f, 0.f, 0.f, 0.f};
        acc = __builtin_amdgcn_mfma_f32_16x16x32_bf16(a, bb, acc, 0, 0, 0);
        int co = i * 16 + l15, k = co >> 5, d = co & 31;
        if (k < 6) {
            #pragma unroll
            for (int r = 0; r < 4; ++r) {
                int n = tb + w * 16 + quad * 4 + r;
                if (n < kN) Yf[(size_t)n * 192 + k * 32 + d] = acc[r];
            }
        } else {
            float cb = convb[d];
            #pragma unroll
            for (int r = 0; r < 4; ++r) {
                int n = tb + w * 16 + quad * 4 + r;
                if (n < kN) obuf[(size_t)n * 32 + d] = acc[r] + cb;
            }
        }
    }
}

// ---- gather-aggregate per node (32 lanes = channels, 8 nodes/group):
// obuf[n] += sum_{e in-edges} (Y5[src] + sum_k hid_k*Yk[src]); fused BN stats.
__global__ __launch_bounds__(256) void agg(
    const int* __restrict__ rowptr, const int* __restrict__ csr_src,
    const int* __restrict__ csr_eid, const unsigned* __restrict__ hp,
    const float* __restrict__ Yf, float* __restrict__ obuf,
    float* __restrict__ statsL)
{
    int t = threadIdx.x;
    int grp = t >> 5, d = t & 31;
    int nbase = blockIdx.x * 64 + grp * 8;
    float s = 0.f, q = 0.f;
    for (int ii = 0; ii < 8; ++ii) {
        int n = nbase + ii;
        if (n >= kN) break;
        float acc = obuf[(size_t)n * 32 + d];
        int j0 = rowptr[n], j1 = rowptr[n + 1];
        for (int j = j0; j < j1; ++j) {
            int src = csr_src[j];
            int eid = csr_eid[j];
            unsigned q0 = hp[(size_t)eid * 3 + 0];
            unsigned q1 = hp[(size_t)eid * 3 + 1];
            unsigned q2 = hp[(size_t)eid * 3 + 2];
            const float* yr = Yf + (size_t)src * 192;
            float m = yr[160 + d];                     // k5 bias-matrix term
            m = fmaf(bf16lo(q0), yr[d], m);
            m = fmaf(bf16hi(q0), yr[32 + d], m);
            m = fmaf(bf16lo(q1), yr[64 + d], m);
            m = fmaf(bf16hi(q1), yr[96 + d], m);
            m = fmaf(bf16lo(q2), yr[128 + d], m);
            acc += m;
        }
        obuf[(size_t)n * 32 + d] = acc;
        s += acc; q += acc * acc;
    }
    __shared__ float ls[256];
    __shared__ float lq[256];
    ls[t] = s; lq[t] = q;
    __syncthreads();
    if (t < 128) { ls[t] += ls[t + 128]; lq[t] += lq[t + 128]; }
    __syncthreads();
    if (t < 64) { ls[t] += ls[t + 64]; lq[t] += lq[t + 64]; }
    __syncthreads();
    if (t < 32) {
        atomicAdd(&statsL[t], ls[t] + ls[t + 32]);
        atomicAdd(&statsL[32 + t], lq[t] + lq[t + 32]);
    }
}

// ---- final BN + prediction dot -> vbuf; init out with pred_b. ----
__global__ __launch_bounds__(256) void bn_norm_final(
    const float* __restrict__ obuf, const float* __restrict__ stats,
    const float* __restrict__ g, const float* __restrict__ b,
    float* __restrict__ vbuf, const float* __restrict__ predW,
    float* __restrict__ out, const float* __restrict__ pred_b)
{
    int idx = blockIdx.x * 256 + threadIdx.x;
    if (idx < kG) out[idx] = pred_b[0];
    if (idx >= kN * 32) return;
    int c = idx & 31;
    float mu = stats[c] * (1.f / kN);
    float var = stats[32 + c] * (1.f / kN) - mu * mu;
    float inv = rsqrtf(var + kEps);
    float v = (obuf[idx] - mu) * inv * g[c] + b[c];
    float pv = v * predW[c];
    #pragma unroll
    for (int off = 16; off > 0; off >>= 1) pv += __shfl_down(pv, off, 32);
    if (c == 0) vbuf[idx >> 5] = pv;
}

// ---- segment readout over sorted batch ids. ----
__global__ __launch_bounds__(256) void seg_readout(
    const float* __restrict__ vbuf, const int* __restrict__ batch,
    float* __restrict__ out)
{
    __shared__ float ls[kG];
    int t = threadIdx.x;
    for (int i = t; i < kG; i += 256) ls[i] = 0.f;
    __syncthreads();
    int base = blockIdx.x * 2048 + t * 8;
    int cur = -1; float acc = 0.f;
    #pragma unroll
    for (int i = 0; i < 8; ++i) {
        int n = base + i;
        if (n >= kN) break;
        int gi = batch[n];
        float val = vbuf[n];
        if (gi != cur) {
            if (cur >= 0) atomicAdd(&ls[cur], acc);
            cur = gi; acc = val;
        } else acc += val;
    }
    if (cur >= 0) atomicAdd(&ls[cur], acc);
    __syncthreads();
    for (int i = t; i < kG; i += 256) {
        float s = ls[i];
        if (s != 0.f) atomicAdd(&out[i], s);
    }
}

} // namespace

extern "C" void kernel_launch(void* const* d_in, const int* in_sizes, int n_in,
                              void* d_out, int out_size, void* d_ws, size_t ws_size,
                              hipStream_t stream)
{
    const float* x      = (const float*)d_in[0];
    const int*   ei     = (const int*)d_in[1];
    const float* ea     = (const float*)d_in[2];
    const int*   batch  = (const int*)d_in[3];
    const float* lin_W  = (const float*)d_in[4];
    const float* lin_b  = (const float*)d_in[5];
    const float* mes_W1 = (const float*)d_in[6];
    const float* mes_b1 = (const float*)d_in[7];
    const float* mes_W2 = (const float*)d_in[8];
    const float* mes_b2 = (const float*)d_in[9];
    const float* root_W = (const float*)d_in[10];
    const float* conv_b = (const float*)d_in[11];
    const float* bn_g   = (const float*)d_in[12];
    const float* bn_b   = (const float*)d_in[13];
    const float* pred_W = (const float*)d_in[14];
    const float* pred_b = (const float*)d_in[15];
    float* out = (float*)d_out;

    // ws: stats[192] | deg[N] rowptr[N+1] cursor[N] csr_src[E] csr_eid[E]
    //     | hbuf[N*32 f32] obuf[N*32 f32] Yf[N*192 f32] hidpk[3*E*3 u32]
    // vbuf[N] overlays Yf (dead after last agg).
    char* wsb = (char*)d_ws;
    float* stats   = (float*)wsb;
    int* deg       = (int*)(wsb + 1024);
    int* rowptr    = deg + kN;
    int* cursor    = rowptr + kN + 1;
    int* csr_src   = cursor + kN;
    int* csr_eid   = csr_src + kE;
    float* hbuf    = (float*)(csr_eid + kE);
    float* obuf    = hbuf + (size_t)kN * 32;
    float* Yf      = obuf + (size_t)kN * 32;
    unsigned* hidpk = (unsigned*)(Yf + (size_t)kN * 192);
    float* vbuf    = Yf;

    zero_init<<<(kN + 255) / 256, 256, 0, stream>>>(deg, stats);
    init_h<<<(kN + 255) / 256, 1024, 0, stream>>>(x, lin_W, lin_b, hbuf);
    hid_pre<<<(kE + 255) / 256, 256, 0, stream>>>(ea, mes_W1, mes_b1, ei, hidpk, deg);
    csr_scan<<<1, 1024, 0, stream>>>(deg, rowptr, cursor);
    csr_fill<<<(kE + 255) / 256, 256, 0, stream>>>(ei, cursor, csr_src, csr_eid);

    for (int l = 0; l < 3; ++l) {
        y_root<<<(kN + 255) / 256, 1024, 0, stream>>>(
            hbuf, obuf, mes_W2 + (size_t)l * 5120, mes_b2 + (size_t)l * 1024,
            root_W + (size_t)l * 1024, conv_b + l * 32,
            stats + (l ? (l - 1) * 64 : 0),
            bn_g + (l ? (l - 1) * 32 : 0), bn_b + (l ? (l - 1) * 32 : 0),
            l == 0 ? 1 : 0, Yf);
        agg<<<(kN + 63) / 64, 256, 0, stream>>>(
            rowptr, csr_src, csr_eid, hidpk + (size_t)l * kE * 3, Yf, obuf,
            stats + l * 64);
    }

    bn_norm_final<<<(kN * 32 + 255) / 256, 256, 0, stream>>>(
        obuf, stats + 128, bn_g + 64, bn_b + 64, vbuf, pred_W, out, pred_b);
    seg_readout<<<(kN + 2047) / 2048, 256, 0, stream>>>(vbuf, batch, out);
}

// Round 7
// 354.385 us; speedup vs baseline: 1.3314x; 1.3314x over previous
//
#include <hip/hip_runtime.h>

namespace {

constexpr int kN = 50000, kE = 200000, kG = 500;
constexpr float kEps = 1e-5f;
constexpr int kNB = (kN + 255) / 256;   // 196 node chunks

typedef short v8s __attribute__((ext_vector_type(8)));
typedef float v4f __attribute__((ext_vector_type(4)));

__device__ __forceinline__ unsigned short bf16rn(float x) {
    unsigned u = __float_as_uint(x);
    return (unsigned short)((u + 0x7FFFu + ((u >> 16) & 1u)) >> 16);
}
__device__ __forceinline__ float bf16lo(unsigned p) { return __uint_as_float(p << 16); }
__device__ __forceinline__ float bf16hi(unsigned p) { return __uint_as_float(p & 0xFFFF0000u); }
__device__ __forceinline__ unsigned pk2(float a, float b) {
    return (unsigned)bf16rn(a) | ((unsigned)bf16rn(b) << 16);
}

// ---- zero deg + stats (ws is re-poisoned to 0xAA before every call). ----
__global__ __launch_bounds__(256) void zero_init(int* __restrict__ deg,
                                                 float* __restrict__ stats) {
    int i = blockIdx.x * 256 + threadIdx.x;
    if (i < kN) deg[i] = 0;
    if (i < 192) stats[i] = 0.f;
}

// ---- h = leaky(x @ lin_W + lin_b), fp32 [n][c], MFMA (A=nodes). ----
__global__ __launch_bounds__(1024) void init_h(
    const float* __restrict__ x, const float* __restrict__ W,
    const float* __restrict__ b, float* __restrict__ hbuf)
{
    __shared__ unsigned short sx[256 * 96];   // [node][feat pad96]
    __shared__ unsigned short sW[32 * 96];    // [c][feat pad96]
    int t = threadIdx.x;
    for (int i = t; i < 256 * 96; i += 1024) sx[i] = 0;
    for (int i = t; i < 32 * 96; i += 1024) sW[i] = 0;
    __syncthreads();
    int tb = blockIdx.x * 256;
    int cnt = min(256, kN - tb);
    for (int i = t; i < cnt * 75; i += 1024) {
        int n = i / 75, f = i - n * 75;
        sx[n * 96 + f] = bf16rn(x[(size_t)tb * 75 + i]);
    }
    for (int i = t; i < 75 * 32; i += 1024) {
        int f = i >> 5, c = i & 31;
        sW[c * 96 + f] = bf16rn(W[i]);
    }
    __syncthreads();
    int l15 = t & 15, quad = (t >> 4) & 3, w = t >> 6;
    #pragma unroll
    for (int tile = 0; tile < 2; ++tile) {
        v4f acc = {0.f, 0.f, 0.f, 0.f};
        #pragma unroll
        for (int kc = 0; kc < 3; ++kc) {
            v8s a  = *(const v8s*)&sx[(w * 16 + l15) * 96 + kc * 32 + quad * 8];
            v8s bb = *(const v8s*)&sW[(tile * 16 + l15) * 96 + kc * 32 + quad * 8];
            acc = __builtin_amdgcn_mfma_f32_16x16x32_bf16(a, bb, acc, 0, 0, 0);
        }
        int c = tile * 16 + l15;
        float bc = b[c];
        #pragma unroll
        for (int r = 0; r < 4; ++r) {
            int n = tb + w * 16 + quad * 4 + r;
            if (n < kN) {
                float v = acc[r] + bc;
                hbuf[(size_t)n * 32 + c] = v > 0.f ? v : 0.01f * v;   // coalesced
            }
        }
    }
}

// ---- hid = relu(ea@W1+b1) for 3 layers (bf16-packed) + deg histogram. ----
__global__ __launch_bounds__(256) void hid_pre(
    const float* __restrict__ ea, const float* __restrict__ W1,
    const float* __restrict__ b1, const int* __restrict__ ei,
    unsigned* __restrict__ hidpk, int* __restrict__ deg)
{
    __shared__ float sE[256 * 13];
    __shared__ float sW[195];
    int t = threadIdx.x;
    for (int i = t; i < 195; i += 256) sW[i] = (i < 180) ? W1[i] : b1[i - 180];
    int base = blockIdx.x * 256;
    int cnt = min(256, kE - base);
    for (int i = t; i < cnt * 12; i += 256) {
        int el = i / 12, f = i - el * 12;
        sE[el * 13 + f] = ea[(size_t)base * 12 + i];
    }
    __syncthreads();
    if (t >= cnt) return;
    int e = base + t;
    atomicAdd(&deg[ei[kE + e]], 1);
    float ef[12];
    #pragma unroll
    for (int j = 0; j < 12; ++j) ef[j] = sE[t * 13 + j];
    #pragma unroll
    for (int l = 0; l < 3; ++l) {
        float h[5];
        #pragma unroll
        for (int k = 0; k < 5; ++k) h[k] = sW[180 + l * 5 + k];
        #pragma unroll
        for (int f = 0; f < 12; ++f)
            #pragma unroll
            for (int k = 0; k < 5; ++k)
                h[k] = fmaf(ef[f], sW[l * 60 + f * 5 + k], h[k]);
        #pragma unroll
        for (int k = 0; k < 5; ++k) h[k] = h[k] > 0.f ? h[k] : 0.f;
        size_t o = ((size_t)l * kE + e) * 3;
        hidpk[o + 0] = pk2(h[0], h[1]);
        hidpk[o + 1] = pk2(h[2], h[3]);
        hidpk[o + 2] = pk2(h[4], 0.f);
    }
}

// ---- scan phase 1: per-block sum of 256 degs. ----
__global__ __launch_bounds__(256) void scan_part(
    const int* __restrict__ deg, int* __restrict__ blkSum)
{
    __shared__ int sc[256];
    int t = threadIdx.x;
    int idx = blockIdx.x * 256 + t;
    sc[t] = (idx < kN) ? deg[idx] : 0;
    __syncthreads();
    #pragma unroll
    for (int off = 128; off > 0; off >>= 1) {
        if (t < off) sc[t] += sc[t + off];
        __syncthreads();
    }
    if (t == 0) blkSum[blockIdx.x] = sc[0];
}

// ---- scan phase 2: exclusive scan of 196 block sums (one tiny block). ----
__global__ __launch_bounds__(256) void scan_top(
    const int* __restrict__ blkSum, int* __restrict__ blkOff,
    int* __restrict__ rowptr)
{
    __shared__ int sc[256];
    int t = threadIdx.x;
    int v = (t < kNB) ? blkSum[t] : 0;
    sc[t] = v;
    __syncthreads();
    #pragma unroll
    for (int off = 1; off < 256; off <<= 1) {
        int u = (t >= off) ? sc[t - off] : 0;
        __syncthreads();
        sc[t] += u;
        __syncthreads();
    }
    if (t < kNB) blkOff[t] = sc[t] - v;        // exclusive
    if (t == kNB - 1) rowptr[kN] = sc[t];      // total (== kE)
}

// ---- scan phase 3: block-local scan + offset -> rowptr & cursor. ----
__global__ __launch_bounds__(256) void scan_add(
    const int* __restrict__ deg, const int* __restrict__ blkOff,
    int* __restrict__ rowptr, int* __restrict__ cursor)
{
    __shared__ int sc[256];
    int t = threadIdx.x;
    int idx = blockIdx.x * 256 + t;
    int v = (idx < kN) ? deg[idx] : 0;
    sc[t] = v;
    __syncthreads();
    #pragma unroll
    for (int off = 1; off < 256; off <<= 1) {
        int u = (t >= off) ? sc[t - off] : 0;
        __syncthreads();
        sc[t] += u;
        __syncthreads();
    }
    if (idx < kN) {
        int p = blkOff[blockIdx.x] + sc[t] - v;   // exclusive prefix
        rowptr[idx] = p;
        cursor[idx] = p;
    }
}

// ---- scatter edges into CSR order (by dst). ----
__global__ __launch_bounds__(256) void csr_fill(
    const int* __restrict__ ei, int* __restrict__ cursor,
    int* __restrict__ csr_src, int* __restrict__ csr_eid)
{
    int e = blockIdx.x * 256 + threadIdx.x;
    if (e >= kE) return;
    int dst = ei[kE + e];
    int pos = atomicAdd(&cursor[dst], 1);
    csr_src[pos] = ei[e];
    csr_eid[pos] = e;
}

// ---- y_root: [256n,32] @ [32,224] MFMA (A=nodes). Y fp32 [n][k][d], k-major
// cols -> coalesced stores. k<6 -> Y, k==6 -> obuf=root+conv_b. BN fused. ----
__global__ __launch_bounds__(1024) void y_root(
    const float* __restrict__ hbuf, float* __restrict__ obuf,
    const float* __restrict__ W2, const float* __restrict__ b2,
    const float* __restrict__ rW, const float* __restrict__ convb,
    const float* __restrict__ stats,
    const float* __restrict__ gPrev, const float* __restrict__ bPrev,
    int first, float* __restrict__ Yf)
{
    __shared__ unsigned short sh[256 * 32];   // [node][c]
    __shared__ unsigned short sB[224 * 32];   // [co=k*32+d][c]
    int t = threadIdx.x;
    int tb = blockIdx.x * 256;
    int cnt = min(256, kN - tb);
    for (int i = t; i < 224 * 32; i += 1024) {
        int co = i >> 5, c = i & 31, k = co >> 5, d = co & 31;
        float v = (k < 5) ? W2[k * 1024 + c * 32 + d]
                : (k == 5) ? b2[c * 32 + d] : rW[c * 32 + d];
        sB[co * 32 + c] = bf16rn(v);
    }
    if (first) {
        #pragma unroll
        for (int j = 0; j < 8; ++j) {
            int idx = t + j * 1024;
            int nl = idx >> 5, c = idx & 31;
            float v = (nl < cnt) ? hbuf[(size_t)(tb + nl) * 32 + c] : 0.f;
            sh[idx] = bf16rn(v);
        }
    } else {
        int c = t & 31;
        float mu = stats[c] * (1.f / kN);
        float var = stats[32 + c] * (1.f / kN) - mu * mu;
        float ivg = rsqrtf(var + kEps) * gPrev[c];
        float bb = bPrev[c];
        #pragma unroll
        for (int j = 0; j < 8; ++j) {
            int idx = t + j * 1024;
            int nl = idx >> 5;
            float v = 0.f;
            if (nl < cnt) {
                float o = obuf[(size_t)(tb + nl) * 32 + c];
                v = (o - mu) * ivg + bb;
                v = v > 0.f ? v : 0.01f * v;
            }
            sh[idx] = bf16rn(v);
        }
    }
    __syncthreads();
    int l15 = t & 15, quad = (t >> 4) & 3, w = t >> 6;
    v8s a = *(const v8s*)&sh[(w * 16 + l15) * 32 + quad * 8];
    #pragma unroll
    for (int i = 0; i < 14; ++i) {
        v8s bb = *(const v8s*)&sB[(i * 16 + l15) * 32 + quad * 8];
        v4f acc = {0.f, 0.f, 0.f, 0.f};
        acc = __builtin_amdgcn_mfma_f32_16x16x32_bf16(a, bb, acc, 0, 0, 0);
        int co = i * 16 + l15, k = co >> 5, d = co & 31;
        if (k < 6) {
            #pragma unroll
            for (int r = 0; r < 4; ++r) {
                int n = tb + w * 16 + quad * 4 + r;
                if (n < kN) Yf[(size_t)n * 192 + k * 32 + d] = acc[r];
            }
        } else {
            float cb = convb[d];
            #pragma unroll
            for (int r = 0; r < 4; ++r) {
                int n = tb + w * 16 + quad * 4 + r;
                if (n < kN) obuf[(size_t)n * 32 + d] = acc[r] + cb;
            }
        }
    }
}

// ---- gather-aggregate per node (32 lanes = channels, 8 nodes/group):
// obuf[n] += sum_{e in-edges} (Y5[src] + sum_k hid_k*Yk[src]); fused BN stats.
__global__ __launch_bounds__(256) void agg(
    const int* __restrict__ rowptr, const int* __restrict__ csr_src,
    const int* __restrict__ csr_eid, const unsigned* __restrict__ hp,
    const float* __restrict__ Yf, float* __restrict__ obuf,
    float* __restrict__ statsL)
{
    int t = threadIdx.x;
    int grp = t >> 5, d = t & 31;
    int nbase = blockIdx.x * 64 + grp * 8;
    float s = 0.f, q = 0.f;
    for (int ii = 0; ii < 8; ++ii) {
        int n = nbase + ii;
        if (n >= kN) break;
        float acc = obuf[(size_t)n * 32 + d];
        int j0 = rowptr[n], j1 = rowptr[n + 1];
        for (int j = j0; j < j1; ++j) {
            int src = csr_src[j];
            int eid = csr_eid[j];
            unsigned q0 = hp[(size_t)eid * 3 + 0];
            unsigned q1 = hp[(size_t)eid * 3 + 1];
            unsigned q2 = hp[(size_t)eid * 3 + 2];
            const float* yr = Yf + (size_t)src * 192;
            float m = yr[160 + d];                     // k5 bias-matrix term
            m = fmaf(bf16lo(q0), yr[d], m);
            m = fmaf(bf16hi(q0), yr[32 + d], m);
            m = fmaf(bf16lo(q1), yr[64 + d], m);
            m = fmaf(bf16hi(q1), yr[96 + d], m);
            m = fmaf(bf16lo(q2), yr[128 + d], m);
            acc += m;
        }
        obuf[(size_t)n * 32 + d] = acc;
        s += acc; q += acc * acc;
    }
    __shared__ float ls[256];
    __shared__ float lq[256];
    ls[t] = s; lq[t] = q;
    __syncthreads();
    if (t < 128) { ls[t] += ls[t + 128]; lq[t] += lq[t + 128]; }
    __syncthreads();
    if (t < 64) { ls[t] += ls[t + 64]; lq[t] += lq[t + 64]; }
    __syncthreads();
    if (t < 32) {
        atomicAdd(&statsL[t], ls[t] + ls[t + 32]);
        atomicAdd(&statsL[32 + t], lq[t] + lq[t + 32]);
    }
}

// ---- final BN + prediction dot -> vbuf; init out with pred_b. ----
__global__ __launch_bounds__(256) void bn_norm_final(
    const float* __restrict__ obuf, const float* __restrict__ stats,
    const float* __restrict__ g, const float* __restrict__ b,
    float* __restrict__ vbuf, const float* __restrict__ predW,
    float* __restrict__ out, const float* __restrict__ pred_b)
{
    int idx = blockIdx.x * 256 + threadIdx.x;
    if (idx < kG) out[idx] = pred_b[0];
    if (idx >= kN * 32) return;
    int c = idx & 31;
    float mu = stats[c] * (1.f / kN);
    float var = stats[32 + c] * (1.f / kN) - mu * mu;
    float inv = rsqrtf(var + kEps);
    float v = (obuf[idx] - mu) * inv * g[c] + b[c];
    float pv = v * predW[c];
    #pragma unroll
    for (int off = 16; off > 0; off >>= 1) pv += __shfl_down(pv, off, 32);
    if (c == 0) vbuf[idx >> 5] = pv;
}

// ---- segment readout over sorted batch ids. ----
__global__ __launch_bounds__(256) void seg_readout(
    const float* __restrict__ vbuf, const int* __restrict__ batch,
    float* __restrict__ out)
{
    __shared__ float ls[kG];
    int t = threadIdx.x;
    for (int i = t; i < kG; i += 256) ls[i] = 0.f;
    __syncthreads();
    int base = blockIdx.x * 2048 + t * 8;
    int cur = -1; float acc = 0.f;
    #pragma unroll
    for (int i = 0; i < 8; ++i) {
        int n = base + i;
        if (n >= kN) break;
        int gi = batch[n];
        float val = vbuf[n];
        if (gi != cur) {
            if (cur >= 0) atomicAdd(&ls[cur], acc);
            cur = gi; acc = val;
        } else acc += val;
    }
    if (cur >= 0) atomicAdd(&ls[cur], acc);
    __syncthreads();
    for (int i = t; i < kG; i += 256) {
        float s = ls[i];
        if (s != 0.f) atomicAdd(&out[i], s);
    }
}

} // namespace

extern "C" void kernel_launch(void* const* d_in, const int* in_sizes, int n_in,
                              void* d_out, int out_size, void* d_ws, size_t ws_size,
                              hipStream_t stream)
{
    const float* x      = (const float*)d_in[0];
    const int*   ei     = (const int*)d_in[1];
    const float* ea     = (const float*)d_in[2];
    const int*   batch  = (const int*)d_in[3];
    const float* lin_W  = (const float*)d_in[4];
    const float* lin_b  = (const float*)d_in[5];
    const float* mes_W1 = (const float*)d_in[6];
    const float* mes_b1 = (const float*)d_in[7];
    const float* mes_W2 = (const float*)d_in[8];
    const float* mes_b2 = (const float*)d_in[9];
    const float* root_W = (const float*)d_in[10];
    const float* conv_b = (const float*)d_in[11];
    const float* bn_g   = (const float*)d_in[12];
    const float* bn_b   = (const float*)d_in[13];
    const float* pred_W = (const float*)d_in[14];
    const float* pred_b = (const float*)d_in[15];
    float* out = (float*)d_out;

    // ws: stats[192] blkSum[256] blkOff[256] | deg[N] rowptr[N+1] cursor[N]
    //     csr_src[E] csr_eid[E] | hbuf[N*32] obuf[N*32] Yf[N*192] hidpk[3*E*3]
    // vbuf[N] overlays Yf (dead after last agg).
    char* wsb = (char*)d_ws;
    float* stats   = (float*)wsb;
    int* blkSum    = (int*)(wsb + 1024);
    int* blkOff    = blkSum + 256;
    int* deg       = blkOff + 256;
    int* rowptr    = deg + kN;
    int* cursor    = rowptr + kN + 1;
    int* csr_src   = cursor + kN;
    int* csr_eid   = csr_src + kE;
    float* hbuf    = (float*)(csr_eid + kE);
    float* obuf    = hbuf + (size_t)kN * 32;
    float* Yf      = obuf + (size_t)kN * 32;
    unsigned* hidpk = (unsigned*)(Yf + (size_t)kN * 192);
    float* vbuf    = Yf;

    zero_init<<<kNB, 256, 0, stream>>>(deg, stats);
    init_h<<<kNB, 1024, 0, stream>>>(x, lin_W, lin_b, hbuf);
    hid_pre<<<(kE + 255) / 256, 256, 0, stream>>>(ea, mes_W1, mes_b1, ei, hidpk, deg);
    scan_part<<<kNB, 256, 0, stream>>>(deg, blkSum);
    scan_top<<<1, 256, 0, stream>>>(blkSum, blkOff, rowptr);
    scan_add<<<kNB, 256, 0, stream>>>(deg, blkOff, rowptr, cursor);
    csr_fill<<<(kE + 255) / 256, 256, 0, stream>>>(ei, cursor, csr_src, csr_eid);

    for (int l = 0; l < 3; ++l) {
        y_root<<<kNB, 1024, 0, stream>>>(
            hbuf, obuf, mes_W2 + (size_t)l * 5120, mes_b2 + (size_t)l * 1024,
            root_W + (size_t)l * 1024, conv_b + l * 32,
            stats + (l ? (l - 1) * 64 : 0),
            bn_g + (l ? (l - 1) * 32 : 0), bn_b + (l ? (l - 1) * 32 : 0),
            l == 0 ? 1 : 0, Yf);
        agg<<<(kN + 63) / 64, 256, 0, stream>>>(
            rowptr, csr_src, csr_eid, hidpk + (size_t)l * kE * 3, Yf, obuf,
            stats + l * 64);
    }

    bn_norm_final<<<(kN * 32 + 255) / 256, 256, 0, stream>>>(
        obuf, stats + 128, bn_g + 64, bn_b + 64, vbuf, pred_W, out, pred_b);
    seg_readout<<<(kN + 2047) / 2048, 256, 0, stream>>>(vbuf, batch, out);
}

// Round 8
// 306.276 us; speedup vs baseline: 1.5406x; 1.1571x over previous
//
#include <hip/hip_runtime.h>

namespace {

constexpr int kN = 50000, kE = 200000, kG = 500;
constexpr float kEps = 1e-5f;
constexpr int kNB = (kN + 255) / 256;   // 196 node chunks

typedef short v8s __attribute__((ext_vector_type(8)));
typedef float v4f __attribute__((ext_vector_type(4)));

__device__ __forceinline__ unsigned short bf16rn(float x) {
    unsigned u = __float_as_uint(x);
    return (unsigned short)((u + 0x7FFFu + ((u >> 16) & 1u)) >> 16);
}
__device__ __forceinline__ float bf16lo(unsigned p) { return __uint_as_float(p << 16); }
__device__ __forceinline__ float bf16hi(unsigned p) { return __uint_as_float(p & 0xFFFF0000u); }
__device__ __forceinline__ unsigned pk2(float a, float b) {
    return (unsigned)bf16rn(a) | ((unsigned)bf16rn(b) << 16);
}

// ---- zero deg + stats (ws re-poisoned to 0xAA before every call). ----
__global__ __launch_bounds__(256) void zero_init(int* __restrict__ deg,
                                                 float* __restrict__ stats) {
    int i = blockIdx.x * 256 + threadIdx.x;
    if (i < kN) deg[i] = 0;
    if (i < 1536) stats[i] = 0.f;   // 3 layers x 8 replicas x 64
}

// ---- degree histogram by dst. ----
__global__ __launch_bounds__(256) void deg_hist(
    const int* __restrict__ ei, int* __restrict__ deg)
{
    int e = blockIdx.x * 256 + threadIdx.x;
    if (e < kE) atomicAdd(&deg[ei[kE + e]], 1);
}

// ---- h = leaky(x @ lin_W + lin_b), fp32 [n][c], MFMA (A=nodes). ----
__global__ __launch_bounds__(1024) void init_h(
    const float* __restrict__ x, const float* __restrict__ W,
    const float* __restrict__ b, float* __restrict__ hbuf)
{
    __shared__ unsigned short sx[256 * 96];   // [node][feat pad96]
    __shared__ unsigned short sW[32 * 96];    // [c][feat pad96]
    int t = threadIdx.x;
    for (int i = t; i < 256 * 96; i += 1024) sx[i] = 0;
    for (int i = t; i < 32 * 96; i += 1024) sW[i] = 0;
    __syncthreads();
    int tb = blockIdx.x * 256;
    int cnt = min(256, kN - tb);
    for (int i = t; i < cnt * 75; i += 1024) {
        int n = i / 75, f = i - n * 75;
        sx[n * 96 + f] = bf16rn(x[(size_t)tb * 75 + i]);
    }
    for (int i = t; i < 75 * 32; i += 1024) {
        int f = i >> 5, c = i & 31;
        sW[c * 96 + f] = bf16rn(W[i]);
    }
    __syncthreads();
    int l15 = t & 15, quad = (t >> 4) & 3, w = t >> 6;
    #pragma unroll
    for (int tile = 0; tile < 2; ++tile) {
        v4f acc = {0.f, 0.f, 0.f, 0.f};
        #pragma unroll
        for (int kc = 0; kc < 3; ++kc) {
            v8s a  = *(const v8s*)&sx[(w * 16 + l15) * 96 + kc * 32 + quad * 8];
            v8s bb = *(const v8s*)&sW[(tile * 16 + l15) * 96 + kc * 32 + quad * 8];
            acc = __builtin_amdgcn_mfma_f32_16x16x32_bf16(a, bb, acc, 0, 0, 0);
        }
        int c = tile * 16 + l15;
        float bc = b[c];
        #pragma unroll
        for (int r = 0; r < 4; ++r) {
            int n = tb + w * 16 + quad * 4 + r;
            if (n < kN) {
                float v = acc[r] + bc;
                hbuf[(size_t)n * 32 + c] = v > 0.f ? v : 0.01f * v;   // coalesced
            }
        }
    }
}

// ---- scan phase 1: per-block sum of 256 degs. ----
__global__ __launch_bounds__(256) void scan_part(
    const int* __restrict__ deg, int* __restrict__ blkSum)
{
    __shared__ int sc[256];
    int t = threadIdx.x;
    int idx = blockIdx.x * 256 + t;
    sc[t] = (idx < kN) ? deg[idx] : 0;
    __syncthreads();
    #pragma unroll
    for (int off = 128; off > 0; off >>= 1) {
        if (t < off) sc[t] += sc[t + off];
        __syncthreads();
    }
    if (t == 0) blkSum[blockIdx.x] = sc[0];
}

// ---- scan phase 2: exclusive scan of block sums (one block). ----
__global__ __launch_bounds__(256) void scan_top(
    const int* __restrict__ blkSum, int* __restrict__ blkOff,
    int* __restrict__ rowptr)
{
    __shared__ int sc[256];
    int t = threadIdx.x;
    int v = (t < kNB) ? blkSum[t] : 0;
    sc[t] = v;
    __syncthreads();
    #pragma unroll
    for (int off = 1; off < 256; off <<= 1) {
        int u = (t >= off) ? sc[t - off] : 0;
        __syncthreads();
        sc[t] += u;
        __syncthreads();
    }
    if (t < kNB) blkOff[t] = sc[t] - v;        // exclusive
    if (t == kNB - 1) rowptr[kN] = sc[t];      // total == kE
}

// ---- scan phase 3: block-local scan + offset -> rowptr & cursor. ----
__global__ __launch_bounds__(256) void scan_add(
    const int* __restrict__ deg, const int* __restrict__ blkOff,
    int* __restrict__ rowptr, int* __restrict__ cursor)
{
    __shared__ int sc[256];
    int t = threadIdx.x;
    int idx = blockIdx.x * 256 + t;
    int v = (idx < kN) ? deg[idx] : 0;
    sc[t] = v;
    __syncthreads();
    #pragma unroll
    for (int off = 1; off < 256; off <<= 1) {
        int u = (t >= off) ? sc[t - off] : 0;
        __syncthreads();
        sc[t] += u;
        __syncthreads();
    }
    if (idx < kN) {
        int p = blkOff[blockIdx.x] + sc[t] - v;
        rowptr[idx] = p;
        cursor[idx] = p;
    }
}

// ---- hid = relu(ea@W1+b1) for 3 layers, written straight into CSR slots:
// hcsr[l][pos] = {h0h1, h2h3, h4_, src}. ----
__global__ __launch_bounds__(256) void hid_pre(
    const float* __restrict__ ea, const float* __restrict__ W1,
    const float* __restrict__ b1, const int* __restrict__ ei,
    int* __restrict__ cursor, uint4* __restrict__ hcsr)
{
    __shared__ float sE[256 * 13];
    __shared__ float sW[195];
    int t = threadIdx.x;
    for (int i = t; i < 195; i += 256) sW[i] = (i < 180) ? W1[i] : b1[i - 180];
    int base = blockIdx.x * 256;
    int cnt = min(256, kE - base);
    for (int i = t; i < cnt * 12; i += 256) {
        int el = i / 12, f = i - el * 12;
        sE[el * 13 + f] = ea[(size_t)base * 12 + i];
    }
    __syncthreads();
    if (t >= cnt) return;
    int e = base + t;
    int src = ei[e];
    int dst = ei[kE + e];
    int pos = atomicAdd(&cursor[dst], 1);
    float ef[12];
    #pragma unroll
    for (int j = 0; j < 12; ++j) ef[j] = sE[t * 13 + j];
    #pragma unroll
    for (int l = 0; l < 3; ++l) {
        float h[5];
        #pragma unroll
        for (int k = 0; k < 5; ++k) h[k] = sW[180 + l * 5 + k];
        #pragma unroll
        for (int f = 0; f < 12; ++f)
            #pragma unroll
            for (int k = 0; k < 5; ++k)
                h[k] = fmaf(ef[f], sW[l * 60 + f * 5 + k], h[k]);
        #pragma unroll
        for (int k = 0; k < 5; ++k) h[k] = h[k] > 0.f ? h[k] : 0.f;
        hcsr[(size_t)l * kE + pos] =
            make_uint4(pk2(h[0], h[1]), pk2(h[2], h[3]), pk2(h[4], 0.f),
                       (unsigned)src);
    }
}

// ---- y_root MFMA (A=weights co=d*8+k, B=nodes): lane holds 4 consecutive k
// for fixed d -> packed bf16 dword stores into Y [n][d][k0..7]us.
// k<6 -> Y, k==6 -> obuf = root + conv_b (fp32). BN of prev layer fused. ----
__global__ __launch_bounds__(1024) void y_root(
    const float* __restrict__ hbuf, float* __restrict__ obuf,
    const float* __restrict__ W2, const float* __restrict__ b2,
    const float* __restrict__ rW, const float* __restrict__ convb,
    const float* __restrict__ statsR,   // prev layer: 8 replicas x 64
    const float* __restrict__ gPrev, const float* __restrict__ bPrev,
    int first, unsigned* __restrict__ Ydw)
{
    __shared__ unsigned short sh[256 * 32];   // [node][c]
    __shared__ unsigned short sB[256 * 32];   // [co=d*8+k][c]
    int t = threadIdx.x;
    int tb = blockIdx.x * 256;
    int cnt = min(256, kN - tb);
    for (int i = t; i < 8192; i += 1024) {
        int co = i >> 5, c = i & 31, d = co >> 3, k = co & 7;
        float v = (k < 5) ? W2[k * 1024 + c * 32 + d]
                : (k == 5) ? b2[c * 32 + d]
                : (k == 6) ? rW[c * 32 + d] : 0.f;
        sB[co * 32 + c] = bf16rn(v);
    }
    if (first) {
        #pragma unroll
        for (int j = 0; j < 8; ++j) {
            int idx = t + j * 1024;
            int nl = idx >> 5, c = idx & 31;
            float v = (nl < cnt) ? hbuf[(size_t)(tb + nl) * 32 + c] : 0.f;
            sh[idx] = bf16rn(v);
        }
    } else {
        int c = t & 31;
        float sum = 0.f, sq = 0.f;
        #pragma unroll
        for (int r = 0; r < 8; ++r) {
            sum += statsR[r * 64 + c];
            sq  += statsR[r * 64 + 32 + c];
        }
        float mu = sum * (1.f / kN);
        float var = sq * (1.f / kN) - mu * mu;
        float ivg = rsqrtf(var + kEps) * gPrev[c];
        float bb = bPrev[c];
        #pragma unroll
        for (int j = 0; j < 8; ++j) {
            int idx = t + j * 1024;
            int nl = idx >> 5;
            float v = 0.f;
            if (nl < cnt) {
                float o = obuf[(size_t)(tb + nl) * 32 + c];
                v = (o - mu) * ivg + bb;
                v = v > 0.f ? v : 0.01f * v;
            }
            sh[idx] = bf16rn(v);
        }
    }
    __syncthreads();
    int l15 = t & 15, quad = (t >> 4) & 3, w = t >> 6;
    int n = tb + w * 16 + l15;
    v8s bn_ = *(const v8s*)&sh[(w * 16 + l15) * 32 + quad * 8];
    #pragma unroll
    for (int i = 0; i < 16; ++i) {
        v8s a = *(const v8s*)&sB[(i * 16 + l15) * 32 + quad * 8];
        v4f acc = {0.f, 0.f, 0.f, 0.f};
        acc = __builtin_amdgcn_mfma_f32_16x16x32_bf16(a, bn_, acc, 0, 0, 0);
        if (n < kN) {
            int cb = i * 16 + quad * 4;         // co of acc[0]; +r consecutive
            int d = cb >> 3, koff = cb & 7;
            if (koff == 0) {
                Ydw[(size_t)n * 128 + d * 4]     = pk2(acc[0], acc[1]); // k0,k1
                Ydw[(size_t)n * 128 + d * 4 + 1] = pk2(acc[2], acc[3]); // k2,k3
            } else {
                Ydw[(size_t)n * 128 + d * 4 + 2] = pk2(acc[0], acc[1]); // k4,k5
                obuf[(size_t)n * 32 + d] = acc[2] + convb[d];           // k6
            }
        }
    }
}

// ---- gather-aggregate: 32 lanes = channels, 2 nodes per group.
// Per edge: ONE uint4 hid+src (broadcast, sequential) + ONE uint4 Y gather.
// Fused BN stats into 8 replica buffers. ----
__global__ __launch_bounds__(256) void agg(
    const int* __restrict__ rowptr, const uint4* __restrict__ hcsr,
    const unsigned short* __restrict__ Yus, float* __restrict__ obuf,
    float* __restrict__ statsR)
{
    int t = threadIdx.x;
    int grp = t >> 5, d = t & 31;
    int nbase = blockIdx.x * 16 + grp * 2;
    float s = 0.f, q = 0.f;
    #pragma unroll
    for (int ii = 0; ii < 2; ++ii) {
        int n = nbase + ii;
        if (n < kN) {
            float acc = obuf[(size_t)n * 32 + d];
            int j0 = rowptr[n], j1 = rowptr[n + 1];
            for (int j = j0; j < j1; ++j) {
                uint4 hq = hcsr[j];
                uint4 p = *(const uint4*)(Yus + (size_t)hq.w * 256 + d * 8);
                float m = bf16hi(p.z);                     // k5 bias-mat term
                m = fmaf(bf16lo(hq.x), bf16lo(p.x), m);
                m = fmaf(bf16hi(hq.x), bf16hi(p.x), m);
                m = fmaf(bf16lo(hq.y), bf16lo(p.y), m);
                m = fmaf(bf16hi(hq.y), bf16hi(p.y), m);
                m = fmaf(bf16lo(hq.z), bf16lo(p.z), m);
                acc += m;
            }
            obuf[(size_t)n * 32 + d] = acc;
            s += acc; q += acc * acc;
        }
    }
    __shared__ float ls[256];
    __shared__ float lq[256];
    ls[t] = s; lq[t] = q;
    __syncthreads();
    if (t < 128) { ls[t] += ls[t + 128]; lq[t] += lq[t + 128]; }
    __syncthreads();
    if (t < 64) { ls[t] += ls[t + 64]; lq[t] += lq[t + 64]; }
    __syncthreads();
    if (t < 32) {
        float* rep = statsR + (blockIdx.x & 7) * 64;
        atomicAdd(&rep[t], ls[t] + ls[t + 32]);
        atomicAdd(&rep[32 + t], lq[t] + lq[t + 32]);
    }
}

// ---- final BN + prediction dot -> vbuf; init out with pred_b. ----
__global__ __launch_bounds__(256) void bn_norm_final(
    const float* __restrict__ obuf, const float* __restrict__ statsR,
    const float* __restrict__ g, const float* __restrict__ b,
    float* __restrict__ vbuf, const float* __restrict__ predW,
    float* __restrict__ out, const float* __restrict__ pred_b)
{
    int idx = blockIdx.x * 256 + threadIdx.x;
    if (idx < kG) out[idx] = pred_b[0];
    if (idx >= kN * 32) return;
    int c = idx & 31;
    float sum = 0.f, sq = 0.f;
    #pragma unroll
    for (int r = 0; r < 8; ++r) {
        sum += statsR[r * 64 + c];
        sq  += statsR[r * 64 + 32 + c];
    }
    float mu = sum * (1.f / kN);
    float var = sq * (1.f / kN) - mu * mu;
    float inv = rsqrtf(var + kEps);
    float v = (obuf[idx] - mu) * inv * g[c] + b[c];
    float pv = v * predW[c];
    #pragma unroll
    for (int off = 16; off > 0; off >>= 1) pv += __shfl_down(pv, off, 32);
    if (c == 0) vbuf[idx >> 5] = pv;
}

// ---- segment readout over sorted batch ids. ----
__global__ __launch_bounds__(256) void seg_readout(
    const float* __restrict__ vbuf, const int* __restrict__ batch,
    float* __restrict__ out)
{
    __shared__ float ls[kG];
    int t = threadIdx.x;
    for (int i = t; i < kG; i += 256) ls[i] = 0.f;
    __syncthreads();
    int base = blockIdx.x * 2048 + t * 8;
    int cur = -1; float acc = 0.f;
    #pragma unroll
    for (int i = 0; i < 8; ++i) {
        int n = base + i;
        if (n >= kN) break;
        int gi = batch[n];
        float val = vbuf[n];
        if (gi != cur) {
            if (cur >= 0) atomicAdd(&ls[cur], acc);
            cur = gi; acc = val;
        } else acc += val;
    }
    if (cur >= 0) atomicAdd(&ls[cur], acc);
    __syncthreads();
    for (int i = t; i < kG; i += 256) {
        float s = ls[i];
        if (s != 0.f) atomicAdd(&out[i], s);
    }
}

} // namespace

extern "C" void kernel_launch(void* const* d_in, const int* in_sizes, int n_in,
                              void* d_out, int out_size, void* d_ws, size_t ws_size,
                              hipStream_t stream)
{
    const float* x      = (const float*)d_in[0];
    const int*   ei     = (const int*)d_in[1];
    const float* ea     = (const float*)d_in[2];
    const int*   batch  = (const int*)d_in[3];
    const float* lin_W  = (const float*)d_in[4];
    const float* lin_b  = (const float*)d_in[5];
    const float* mes_W1 = (const float*)d_in[6];
    const float* mes_b1 = (const float*)d_in[7];
    const float* mes_W2 = (const float*)d_in[8];
    const float* mes_b2 = (const float*)d_in[9];
    const float* root_W = (const float*)d_in[10];
    const float* conv_b = (const float*)d_in[11];
    const float* bn_g   = (const float*)d_in[12];
    const float* bn_b   = (const float*)d_in[13];
    const float* pred_W = (const float*)d_in[14];
    const float* pred_b = (const float*)d_in[15];
    float* out = (float*)d_out;

    // ws: stats[3*512] | deg[N] rowptr[N+1] cursor[N] blkSum[256] blkOff[256]
    //     | hbuf[N*32 f] obuf[N*32 f] | Y[N*256 us] | hcsr[3*E uint4]
    // vbuf[N] overlays Y (dead after last agg).
    char* wsb = (char*)d_ws;
    float* stats   = (float*)wsb;                       // 1536 floats
    int* deg       = (int*)(wsb + 8192);
    int* rowptr    = deg + kN;
    int* cursor    = rowptr + kN + 1;
    int* blkSum    = cursor + kN;
    int* blkOff    = blkSum + 256;
    float* hbuf    = (float*)(blkOff + 256);
    float* obuf    = hbuf + (size_t)kN * 32;
    unsigned short* Yus = (unsigned short*)(obuf + (size_t)kN * 32);
    unsigned* Ydw  = (unsigned*)Yus;
    uint4* hcsr    = (uint4*)(Yus + (size_t)kN * 256);
    float* vbuf    = (float*)Yus;

    zero_init<<<kNB, 256, 0, stream>>>(deg, stats);
    deg_hist<<<(kE + 255) / 256, 256, 0, stream>>>(ei, deg);
    init_h<<<kNB, 1024, 0, stream>>>(x, lin_W, lin_b, hbuf);
    scan_part<<<kNB, 256, 0, stream>>>(deg, blkSum);
    scan_top<<<1, 256, 0, stream>>>(blkSum, blkOff, rowptr);
    scan_add<<<kNB, 256, 0, stream>>>(deg, blkOff, rowptr, cursor);
    hid_pre<<<(kE + 255) / 256, 256, 0, stream>>>(ea, mes_W1, mes_b1, ei,
                                                  cursor, hcsr);

    for (int l = 0; l < 3; ++l) {
        y_root<<<kNB, 1024, 0, stream>>>(
            hbuf, obuf, mes_W2 + (size_t)l * 5120, mes_b2 + (size_t)l * 1024,
            root_W + (size_t)l * 1024, conv_b + l * 32,
            stats + (l ? (l - 1) * 512 : 0),
            bn_g + (l ? (l - 1) * 32 : 0), bn_b + (l ? (l - 1) * 32 : 0),
            l == 0 ? 1 : 0, Ydw);
        agg<<<(kN + 15) / 16, 256, 0, stream>>>(
            rowptr, hcsr + (size_t)l * kE, Yus, obuf, stats + l * 512);
    }

    bn_norm_final<<<(kN * 32 + 255) / 256, 256, 0, stream>>>(
        obuf, stats + 2 * 512, bn_g + 64, bn_b + 64, vbuf, pred_W, out, pred_b);
    seg_readout<<<(kN + 2047) / 2048, 256, 0, stream>>>(vbuf, batch, out);
}